// Round 3
// baseline (400.203 us; speedup 1.0000x reference)
//
#include <hip/hip_runtime.h>
#include <cstdint>
#include <cstddef>

#define GK0 0.7978845608028654f
#define GC1 0.044715f

typedef __attribute__((ext_vector_type(8))) short short8;
typedef __attribute__((ext_vector_type(4))) float floatx4;

__device__ __forceinline__ unsigned short f2bf(float f) {
  union { float f; unsigned int u; } v; v.f = f;
  unsigned int r = v.u + 0x7fffu + ((v.u >> 16) & 1u);   // RNE
  return (unsigned short)(r >> 16);
}

// ---- weights: [co][ci][3][3] f32 -> wt[khw][co][ci] bf16; also zero out ----
__global__ void k_wt(const float* __restrict__ w, unsigned short* __restrict__ wt,
                     float* __restrict__ out) {
  if (blockIdx.x == 0) {
    for (int i = threadIdx.x; i < 32 * 128; i += 256) out[i] = 0.0f;
  }
  int t = blockIdx.x * 256 + threadIdx.x;
  if (t >= 128 * 64 * 9) return;
  int co = t / 576; int r = t - co * 576; int ci = r / 9; int khw = r - ci * 9;
  wt[(khw * 128 + co) * 64 + ci] = f2bf(w[t]);
}

// ---- fused NCHW->bf16 staging + conv + bias + gelu + pool ----
// grid (2 wtiles, 63 htiles, 32 b), block 256 (4 waves)
// block tile: M=128 co x N=128 pos (2 h-rows x 64 w), K=576 (9 khw x 64 ci)
// launch_bounds(256,2): 256 regs/wave cap -> NO SPILLS (R2's 64MB scratch traffic
// came from the (256,4)=128-reg cap; acc(64)+frags(48)+addr needs ~150)
__global__ __launch_bounds__(256, 2) void k_conv(
    const float* __restrict__ x, const unsigned short* __restrict__ wt,
    const float* __restrict__ bias, float* __restrict__ out) {
  // x tile: 4 rows x 66 w x 64 ci (shorts), w-entry stride padded 64->72 shorts
  __shared__ unsigned short xs[4 * 66 * 72];
  const int tid = threadIdx.x;
  const int b = blockIdx.z, h0 = blockIdx.y * 2, w0 = blockIdx.x * 64;
  const int lane = tid & 63, wave = tid >> 6;

  { // coalesced staging: wave = hi row, lane = w (contiguous 256B global loads),
    // 8 ci-planes packed per ds_write_b128
    const int hi = wave;
    const float* xrow = x + ((size_t)(b * 64) * 128 + (h0 + hi)) * 128 + w0;
    unsigned short* dstrow = xs + (hi * 66 + lane) * 72;
#pragma unroll
    for (int cc = 0; cc < 8; cc++) {
      const float* p = xrow + (size_t)cc * 8 * 16384 + lane;
      short8 v;
#pragma unroll
      for (int j = 0; j < 8; j++) v[j] = (short)f2bf(p[(size_t)j * 16384]);
      *(short8*)(dstrow + cc * 8) = v;
    }
    if (lane < 16) {  // w-entries 64,65 (halo); zero when out of range (w0=64 tile)
      const int e = 64 + (lane & 1), cc = lane >> 1;
      const bool ok = (w0 + e) < 128;
      const float* p = x + ((size_t)(b * 64 + cc * 8) * 128 + (h0 + hi)) * 128 + w0 + e;
      short8 v;
#pragma unroll
      for (int j = 0; j < 8; j++) v[j] = ok ? (short)f2bf(p[(size_t)j * 16384]) : (short)0;
      *(short8*)(xs + (hi * 66 + e) * 72 + cc * 8) = v;
    }
  }
  __syncthreads();

  const int wm = wave & 1, wn = wave >> 1;      // 2x2 wave grid: co-half, pos-half
  const int m = lane & 15, q = lane >> 4;

  floatx4 acc[4][4];
#pragma unroll
  for (int i = 0; i < 4; i++)
#pragma unroll
    for (int j = 0; j < 4; j++) acc[i][j] = (floatx4){0.f, 0.f, 0.f, 0.f};

  // A (weights): lane holds w[co = wm*64+mt*16+m][ci = cb + q*8 + j]
  const unsigned short* wbase = wt + ((wm * 64 + m) * 64 + q * 8);
  // B (patches): lane holds xs[(wn+kh)][nt*16+m+kw][ci = cb + q*8 + j]
  int bb[4];
#pragma unroll
  for (int nt = 0; nt < 4; nt++) bb[nt] = (wn * 66 + nt * 16 + m) * 72 + q * 8;

  short8 a_cur[4], a_nxt[4];
#pragma unroll
  for (int mt = 0; mt < 4; mt++) a_cur[mt] = *(const short8*)(wbase + mt * 1024);

#pragma unroll
  for (int kk = 0; kk < 18; kk++) {
    const int khw = kk >> 1, cb = (kk & 1) << 5;
    const int kh = khw / 3, kw = khw - kh * 3;
    if (kk < 17) {  // register double-buffer next A-fragments (hide L2 latency)
      const int khw2 = (kk + 1) >> 1, cb2 = ((kk + 1) & 1) << 5;
      const unsigned short* p = wbase + khw2 * 8192 + cb2;
#pragma unroll
      for (int mt = 0; mt < 4; mt++) a_nxt[mt] = *(const short8*)(p + mt * 1024);
    }
    short8 bf[4];
    const int off = (kh * 66 + kw) * 72 + cb;
#pragma unroll
    for (int nt = 0; nt < 4; nt++) bf[nt] = *(const short8*)(&xs[bb[nt] + off]);
#pragma unroll
    for (int mt = 0; mt < 4; mt++)
#pragma unroll
      for (int nt = 0; nt < 4; nt++)
        acc[mt][nt] = __builtin_amdgcn_mfma_f32_16x16x32_bf16(a_cur[mt], bf[nt], acc[mt][nt], 0, 0, 0);
#pragma unroll
    for (int mt = 0; mt < 4; mt++) a_cur[mt] = a_nxt[mt];
  }

  // epilogue: bias + fast tanh-GELU (y*sigmoid(2u)) + masked pool
  // D layout: col(n)=lane&15, row(m)=q*4+reg
  const float inv_area = 1.0f / (126.0f * 126.0f);
  float* orow = out + b * 128;
#pragma unroll
  for (int mt = 0; mt < 4; mt++) {
#pragma unroll
    for (int r = 0; r < 4; r++) {
      const int co = wm * 64 + mt * 16 + q * 4 + r;
      const float bv = bias[co];
      float s = 0.0f;
#pragma unroll
      for (int nt = 0; nt < 4; nt++) {
        float y = acc[mt][nt][r] + bv;
        float u = GK0 * (y + GC1 * y * y * y);
        float e = __expf(-2.0f * u);                          // v_exp_f32 path
        float g = y * __builtin_amdgcn_rcpf(1.0f + e);        // == 0.5y(1+tanh(u))
        if (w0 + nt * 16 + m < 126) s += g;                   // mask padded w=126,127
      }
#pragma unroll
      for (int d = 1; d < 16; d <<= 1) s += __shfl_xor(s, d, 64);  // reduce over n-lanes
      if (m == 0) atomicAdd(&orow[co], s * inv_area);
    }
  }
}

extern "C" void kernel_launch(void* const* d_in, const int* in_sizes, int n_in,
                              void* d_out, int out_size, void* d_ws, size_t ws_size,
                              hipStream_t stream) {
  const float* x    = (const float*)d_in[0];
  const float* w    = (const float*)d_in[1];
  const float* bias = (const float*)d_in[2];
  float* out = (float*)d_out;

  unsigned short* wbuf = (unsigned short*)d_ws;   // 9*128*64 bf16 = 144 KiB
  if (ws_size < (size_t)9 * 128 * 64 * 2) return;

  k_wt<<<288, 256, 0, stream>>>(w, wbuf, out);
  k_conv<<<dim3(2, 63, 32), 256, 0, stream>>>(x, wbuf, bias, out);
}